// Round 23
// baseline (1958.386 us; speedup 1.0000x reference)
//
#include <hip/hip_runtime.h>
#include <hip/hip_bf16.h>
#include <hip/hip_fp8.h>
#include <math.h>

#define IGNORE_INDEX (-100)

static constexpr int Dc = 1024, Vc = 128000;
static constexpr int Mrows = 2048;        // B*S
static constexpr int Kdim = 1024;
static constexpr int NT128 = Kdim / 128;  // 8 k-tiles of 128 fp8 elems
static constexpr int NCHUNK = Vc / 64;    // 2000 partial chunks (64 cols) per row

typedef int i32x4 __attribute__((ext_vector_type(4)));
typedef int i32x8 __attribute__((ext_vector_type(8)));
typedef float f32x4_t __attribute__((ext_vector_type(4)));

// ---- cast fp32 -> fp8 e4m3, FRAGMENT-MAJOR pack for 16x16x128 MX MFMA ------
// Frag tile = 16 rows x 128 k = 2048 B: lane = (row&15) + 16*(k>>5),
// byte pos = ((k>>4)&1)*1024 + lane*16 + (k&15). Any k-bijection is correct as
// long as A and B packs share it (k-permutation-invariant dot; unit scales --
// semantics verified R20-R22: absmax 0.0 with the 32x32x64 sibling).
// R22 lesson: the 32x32x64 shape's f32x16 acc (16-consecutive-reg tuples)
// makes the allocator spill regardless of total demand; 16x16x128 uses f32x4
// accs (the m148-proven 1628 TF plain-HIP MX shape).
__global__ void cast_f32_fp8_pack(const float* __restrict__ in, uchar* __restrict__ out,
                                  size_t n8) {
  size_t i = (size_t)blockIdx.x * blockDim.x + threadIdx.x;
  size_t stride = (size_t)gridDim.x * blockDim.x;
  for (; i < n8; i += stride) {
    size_t q = i * 8;                      // output byte
    size_t ftile = q >> 11;                // rt*NT128 + kt
    int rem = (int)(q & 2047);
    int chunk = rem >> 10;                 // (k>>4)&1
    int lane = (rem >> 4) & 63;
    int sub0 = rem & 15;                   // 0 or 8
    size_t rt = ftile >> 3;                // / NT128
    int kt = (int)(ftile & 7);
    size_t row = rt * 16 + (lane & 15);
    int k = kt * 128 + (lane >> 4) * 32 + chunk * 16 + sub0;
    const float* p = in + row * Kdim + k;
    float4 v0 = *reinterpret_cast<const float4*>(p);
    float4 v1 = *reinterpret_cast<const float4*>(p + 4);
    union { uchar b[8]; unsigned long long u; } o;
    o.b[0] = __hip_fp8_e4m3(v0.x).__x; o.b[1] = __hip_fp8_e4m3(v0.y).__x;
    o.b[2] = __hip_fp8_e4m3(v0.z).__x; o.b[3] = __hip_fp8_e4m3(v0.w).__x;
    o.b[4] = __hip_fp8_e4m3(v1.x).__x; o.b[5] = __hip_fp8_e4m3(v1.y).__x;
    o.b[6] = __hip_fp8_e4m3(v1.z).__x; o.b[7] = __hip_fp8_e4m3(v1.w).__x;
    reinterpret_cast<unsigned long long*>(out)[i] = o.u;
  }
}

// ---------------- target logits: fp32 dot(hidden[r], weight[t[r]]) — exact ----
__global__ void tgt_kernel(const float* __restrict__ hidden, const float* __restrict__ weight,
                           const int* __restrict__ targets, float* __restrict__ tgt) {
  int row = blockIdx.x * 4 + (threadIdx.x >> 6);
  int lane = threadIdx.x & 63;
  if (row >= Mrows) return;
  int t = targets[row];
  float sum = 0.f;
  if (t != IGNORE_INDEX) {
    const float* h = hidden + (size_t)row * Kdim;
    const float* wv = weight + (size_t)t * Kdim;
    for (int k = lane * 4; k < Kdim; k += 64 * 4) {
      float4 a = *reinterpret_cast<const float4*>(h + k);
      float4 b = *reinterpret_cast<const float4*>(wv + k);
      sum += a.x * b.x + a.y * b.y + a.z * b.z + a.w * b.w;
    }
  }
  #pragma unroll
  for (int d = 1; d < 64; d <<= 1) sum += __shfl_xor(sum, d);
  if (lane == 0) tgt[row] = sum;
}

// -- 128x128 4-wave dbuf MX-FP8 (16x16x128) GEMM + fused partial LSE ---------
// m148-profile: wave = 64x64 = 4x4 frags of 16x16x128; acc = 4x4 f32x4 (64
// regs, 4-aligned) + operands 8x i32x8 (64) -> ~150 demand, cap 256 via
// launch_bounds(256,2). LDS dbuf 2x32KB -> 2 blocks/CU = 2 waves/SIMD (R7:
// 1 wave/SIMD is latency-fragile). 8 K-tiles; simple vmcnt(0) dbuf (R13 form).
#define MXFMA(A, B, C) __builtin_amdgcn_mfma_scale_f32_16x16x128_f8f6f4( \
    (A), (B), (C), 0, 0, 0, 0x7F7F7F7F, 0, 0x7F7F7F7F)
#define GLDS(g, l) __builtin_amdgcn_global_load_lds( \
    (const __attribute__((address_space(1))) void*)(g), \
    (__attribute__((address_space(3))) void*)(l), 16, 0, 0)

__global__ __launch_bounds__(256, 2) void gemm_lse_mx(const uchar* __restrict__ Apk,
                                                      const uchar* __restrict__ Bpk,
                                                      float2* __restrict__ part) {
  __shared__ uchar lds[2][32768];      // [dbuf][A 8 frags 16KB | B 8 frags 16KB]
  const int tid = threadIdx.x;
  const int wid = tid >> 6, lane = tid & 63;
  const int wr = wid >> 1, wc = wid & 1;        // 2x2 wave grid, wave = 64x64 out
  const int l15 = lane & 15, l16 = lane >> 4;
  const int bid = blockIdx.x;
  const int mb = bid & 15;             // Mrows/128 = 16 M-blocks
  const int nb = bid >> 4;             // 0..999 (V/128)

  // staging: A 1024 chunks (c = j*256+tid, j=0..3), B same; frag f = c>>7
  const uchar* sgA[4]; const uchar* sgB[4];
  #pragma unroll
  for (int j = 0; j < 4; ++j) {
    int c = j * 256 + tid;
    int f = c >> 7, idx = c & 127;
    sgA[j] = Apk + ((size_t)(mb * 8 + f) * NT128) * 2048 + idx * 16;
    sgB[j] = Bpk + ((size_t)(nb * 8 + f) * NT128) * 2048 + idx * 16;
  }

  f32x4_t acc[4][4];
  #pragma unroll
  for (int i = 0; i < 4; ++i)
    #pragma unroll
    for (int j = 0; j < 4; ++j)
      acc[i][j] = (f32x4_t){0.f, 0.f, 0.f, 0.f};

  #define STAGE(bufp, kt) do { \
    _Pragma("unroll") \
    for (int j = 0; j < 4; ++j) { \
      int c = j * 256 + tid; \
      GLDS(sgA[j] + (size_t)(kt) * 2048, (bufp) + c * 16); \
      GLDS(sgB[j] + (size_t)(kt) * 2048, (bufp) + 16384 + c * 16); \
    } \
  } while (0)

  // prologue: stage tile 0, drain
  STAGE(lds[0], 0);
  asm volatile("s_waitcnt vmcnt(0)" ::: "memory");
  __builtin_amdgcn_s_barrier();

  for (int t = 0; t < NT128; ++t) {
    const int buf = t & 1;
    if (t + 1 < NT128) STAGE(lds[buf ^ 1], t + 1);
    const uchar* Ar = lds[buf];
    const uchar* Br = lds[buf] + 16384;
    i32x8 a8[4], b8[4];
    #pragma unroll
    for (int mi = 0; mi < 4; ++mi) {
      const uchar* base = Ar + (wr * 4 + mi) * 2048 + lane * 16;
      i32x4 lo = *reinterpret_cast<const i32x4*>(base);
      i32x4 hi = *reinterpret_cast<const i32x4*>(base + 1024);
      a8[mi] = __builtin_shufflevector(lo, hi, 0, 1, 2, 3, 4, 5, 6, 7);
    }
    #pragma unroll
    for (int ni = 0; ni < 4; ++ni) {
      const uchar* base = Br + (wc * 4 + ni) * 2048 + lane * 16;
      i32x4 lo = *reinterpret_cast<const i32x4*>(base);
      i32x4 hi = *reinterpret_cast<const i32x4*>(base + 1024);
      b8[ni] = __builtin_shufflevector(lo, hi, 0, 1, 2, 3, 4, 5, 6, 7);
    }
    __builtin_amdgcn_s_setprio(1);
    #pragma unroll
    for (int mi = 0; mi < 4; ++mi)
      #pragma unroll
      for (int ni = 0; ni < 4; ++ni)
        acc[mi][ni] = MXFMA(a8[mi], b8[ni], acc[mi][ni]);
    __builtin_amdgcn_s_setprio(0);
    if (t + 1 < NT128) {
      asm volatile("s_waitcnt vmcnt(0)" ::: "memory");
      __builtin_amdgcn_s_barrier();
    }
  }
  #undef STAGE

  // fused partial-LSE epilogue (R13-verified 16x16 form):
  // acc[mi][ni][j]: row = wr*64+mi*16+l16*4+j, col = wc*64+ni*16+l15
  // (m89 C/D layout; dtype/shape-independent per m121-128)
  const int chunk = nb * 2 + wc;
  #pragma unroll
  for (int mi = 0; mi < 4; ++mi) {
    #pragma unroll
    for (int j = 0; j < 4; ++j) {
      float v0 = acc[mi][0][j], v1 = acc[mi][1][j], v2 = acc[mi][2][j], v3 = acc[mi][3][j];
      float mloc = fmaxf(fmaxf(v0, v1), fmaxf(v2, v3));
      #pragma unroll
      for (int d = 1; d < 16; d <<= 1) mloc = fmaxf(mloc, __shfl_xor(mloc, d));
      float sloc = __expf(v0 - mloc) + __expf(v1 - mloc) +
                   __expf(v2 - mloc) + __expf(v3 - mloc);
      #pragma unroll
      for (int d = 1; d < 16; d <<= 1) sloc += __shfl_xor(sloc, d);
      if (l15 == 0) {
        int grow = mb * 128 + wr * 64 + mi * 16 + l16 * 4 + j;
        part[(size_t)grow * NCHUNK + chunk] = make_float2(mloc, sloc);
      }
    }
  }
}

// ---------------- per-row merge of partials -> nll[row] ----------------
__device__ __forceinline__ void merge_ms(float& m, float& s, float m2, float s2) {
  if (m2 > m) { s = s * __expf(m - m2) + s2; m = m2; }
  else        { s += s2 * __expf(m2 - m); }
}

__global__ void lse_reduce(const float2* __restrict__ part, const float* __restrict__ tgt,
                           const int* __restrict__ targets, float* __restrict__ nll) {
  int row = blockIdx.x;
  const float2* p = part + (size_t)row * NCHUNK;
  float m = -INFINITY, s = 0.f;
  for (int c = threadIdx.x; c < NCHUNK; c += blockDim.x) {
    float2 v = p[c];
    merge_ms(m, s, v.x, v.y);
  }
  #pragma unroll
  for (int d = 1; d < 64; d <<= 1) {
    float m2 = __shfl_xor(m, d), s2 = __shfl_xor(s, d);
    merge_ms(m, s, m2, s2);
  }
  __shared__ float sm[4], ss[4];
  int wid = threadIdx.x >> 6, lane = threadIdx.x & 63;
  if (lane == 0) { sm[wid] = m; ss[wid] = s; }
  __syncthreads();
  if (threadIdx.x == 0) {
    #pragma unroll
    for (int w2 = 1; w2 < 4; ++w2) merge_ms(m, s, sm[w2], ss[w2]);
    int t = targets[row];
    float out = 0.f;
    if (t != IGNORE_INDEX) out = m + logf(s) - tgt[row];
    nll[row] = out;
  }
}

// ---------------- final scalar: sum(nll)/count ----------------
__global__ void final_kernel(const float* __restrict__ nll, const int* __restrict__ targets,
                             float* __restrict__ out) {
  float sum = 0.f, cnt = 0.f;
  for (int i = threadIdx.x; i < Mrows; i += 64) {
    sum += nll[i];
    cnt += (targets[i] != IGNORE_INDEX) ? 1.f : 0.f;
  }
  #pragma unroll
  for (int d = 1; d < 64; d <<= 1) {
    sum += __shfl_xor(sum, d);
    cnt += __shfl_xor(cnt, d);
  }
  if (threadIdx.x == 0)
    out[0] = (cnt == 0.f) ? sum : sum / fmaxf(cnt, 1.f);
}

extern "C" void kernel_launch(void* const* d_in, const int* in_sizes, int n_in,
                              void* d_out, int out_size, void* d_ws, size_t ws_size,
                              hipStream_t stream) {
  const float* hidden = (const float*)d_in[0];   // [2,1024,1024] f32
  const float* weight = (const float*)d_in[1];   // [128000,1024] f32
  const int* targets  = (const int*)d_in[2];     // [2,1024] i32
  float* out = (float*)d_out;

  char* ws = (char*)d_ws;
  size_t off = 0;
  uchar* w8 = (uchar*)(ws + off); off += (size_t)Vc * Dc;                  // 128 MB
  uchar* h8 = (uchar*)(ws + off); off += (size_t)Mrows * Dc;               // 2 MB
  float2* part = (float2*)(ws + off); off += (size_t)Mrows * NCHUNK * sizeof(float2); // 32.8 MB
  float* tgt = (float*)(ws + off); off += Mrows * sizeof(float);
  float* nll = (float*)(ws + off); off += Mrows * sizeof(float);
  (void)ws_size; (void)in_sizes; (void)n_in; (void)out_size;

  cast_f32_fp8_pack<<<2048, 256, 0, stream>>>(weight, w8, (size_t)Vc * Dc / 8);
  cast_f32_fp8_pack<<<256, 256, 0, stream>>>(hidden, h8, (size_t)Mrows * Dc / 8);
  tgt_kernel<<<Mrows / 4, 256, 0, stream>>>(hidden, weight, targets, tgt);

  gemm_lse_mx<<<16000, 256, 0, stream>>>(h8, w8, part);  // mb=bid&15, nb=bid>>4

  lse_reduce<<<Mrows, 256, 0, stream>>>(part, tgt, targets, nll);
  final_kernel<<<1, 64, 0, stream>>>(nll, targets, out);
}

// Round 24
// 563.811 us; speedup vs baseline: 3.4735x; 3.4735x over previous
//
#include <hip/hip_runtime.h>
#include <hip/hip_bf16.h>
#include <hip/hip_fp8.h>
#include <math.h>

#define IGNORE_INDEX (-100)

static constexpr int Dc = 1024, Vc = 128000;
static constexpr int Mrows = 2048;        // B*S
static constexpr int Kdim = 1024;
static constexpr int BK = 64;             // fp8: 64 elems = 64 B LDS rows
static constexpr int NT = Kdim / BK;      // 16 K-tiles
static constexpr int NCHUNK = Vc / 64;    // 2000 partial chunks per row

typedef float f32x4_t __attribute__((ext_vector_type(4)));

// ------- cast fp32 -> fp8 e4m3 with PRE-SWIZZLED layout (8B granularity) -----
// (R18-verified: GEMM passed, absmax 0, SQ_LDS_BANK_CONFLICT = 0)
// Within every 32B k-group of a row, 8B slot s is stored at s ^ ((row>>2)&3).
// Bakes the LDS bank swizzle into the global buffer so GEMM staging stays
// 16B-linear while ds_read_b64 hits all 32 banks per 16-lane group.
__global__ void cast_f32_fp8_swz(const float* __restrict__ in, uchar* __restrict__ out,
                                 size_t n8) {
  size_t i = (size_t)blockIdx.x * blockDim.x + threadIdx.x;
  size_t stride = (size_t)gridDim.x * blockDim.x;
  for (; i < n8; i += stride) {
    size_t byte0 = i * 8;                 // logical fp8 byte index (slot-aligned)
    size_t row = byte0 >> 10;             // 1024 B per K-row
    int s = (int)(byte0 >> 3) & 3;        // slot within 32B group
    int sw = s ^ ((int)(row >> 2) & 3);
    size_t obyte = (byte0 & ~(size_t)31) | ((size_t)sw << 3);
    float4 v0 = *reinterpret_cast<const float4*>(in + byte0);
    float4 v1 = *reinterpret_cast<const float4*>(in + byte0 + 4);
    union { uchar b[8]; unsigned long long u; } p;
    p.b[0] = __hip_fp8_e4m3(v0.x).__x; p.b[1] = __hip_fp8_e4m3(v0.y).__x;
    p.b[2] = __hip_fp8_e4m3(v0.z).__x; p.b[3] = __hip_fp8_e4m3(v0.w).__x;
    p.b[4] = __hip_fp8_e4m3(v1.x).__x; p.b[5] = __hip_fp8_e4m3(v1.y).__x;
    p.b[6] = __hip_fp8_e4m3(v1.z).__x; p.b[7] = __hip_fp8_e4m3(v1.w).__x;
    *reinterpret_cast<unsigned long long*>(out + obyte) = p.u;
  }
}

// ---------------- target logits: fp32 dot(hidden[r], weight[t[r]]) — exact ----
__global__ void tgt_kernel(const float* __restrict__ hidden, const float* __restrict__ weight,
                           const int* __restrict__ targets, float* __restrict__ tgt) {
  int row = blockIdx.x * 4 + (threadIdx.x >> 6);
  int lane = threadIdx.x & 63;
  if (row >= Mrows) return;
  int t = targets[row];
  float sum = 0.f;
  if (t != IGNORE_INDEX) {
    const float* h = hidden + (size_t)row * Kdim;
    const float* wv = weight + (size_t)t * Kdim;
    for (int k = lane * 4; k < Kdim; k += 64 * 4) {
      float4 a = *reinterpret_cast<const float4*>(h + k);
      float4 b = *reinterpret_cast<const float4*>(wv + k);
      sum += a.x * b.x + a.y * b.y + a.z * b.z + a.w * b.w;
    }
  }
  #pragma unroll
  for (int d = 1; d < 64; d <<= 1) sum += __shfl_xor(sum, d);
  if (lane == 0) tgt[row] = sum;
}

// -- 128x256 8-wave 2-BLOCK/CU ring-3 FP8 GEMM (BK=64) + fused partial LSE ---
// REVERT from MX (R20-R23: mfma_scale codegen spills acc to scratch in every
// shape/tile config — toolchain-dead; numerics were correct). Base = R18
// (632us verified, 0 conflicts, VGPR 64 + acc 64 = exactly the (512,4) cap).
// Only change vs R18: BK=64 per ring slot -> 16 iterations instead of 32,
// halving barrier+vmcnt events at identical register structure and read
// geometry (per-kstep a[4]/b[4] longs; koff formula unchanged; 2-way bank
// aliasing = free). Staging 3 GLDS/thread/tile -> counted vmcnt(3).
#define MFMA_FP8(A, B, C) __builtin_amdgcn_mfma_f32_16x16x32_fp8_fp8((A), (B), (C), 0, 0, 0)
#define GLDS(g, l) __builtin_amdgcn_global_load_lds( \
    (const __attribute__((address_space(1))) void*)(g), \
    (__attribute__((address_space(3))) void*)(l), 16, 0, 0)

__global__ __launch_bounds__(512, 4) void gemm_lse_fp8(const uchar* __restrict__ A8,
                                                       const uchar* __restrict__ B8,
                                                       float2* __restrict__ part) {
  __shared__ uchar lds[3][24576];      // [ring][A(128x64B)=8KB | B(256x64B)=16KB]
  const int tid = threadIdx.x;
  const int wid = tid >> 6, lane = tid & 63;
  const int wr = wid >> 2, wc = wid & 3;        // 2M x 4N wave grid, wave = 64x64 out
  const int l15 = lane & 15, l16 = lane >> 4;
  const int bid = blockIdx.x;
  const int mb = bid & 15;             // 16 M-blocks share one B panel
  const int nb = bid >> 4;             // 0..499

  // staging sources (16B-linear; data pre-swizzled by cast kernel).
  // A: 512 chunks (row tid>>2, pos tid&3); B: 1024 chunks (c=tid, tid+512).
  const uchar* gA = A8 + (size_t)(mb * 128) * 1024;
  const uchar* gB = B8 + (size_t)(nb * 256) * 1024;
  const uchar* sgA  = gA + (size_t)(tid >> 2) * 1024 + (tid & 3) * 16;
  const uchar* sgB0 = gB + (size_t)(tid >> 2) * 1024 + (tid & 3) * 16;
  const uchar* sgB1 = gB + (size_t)((tid + 512) >> 2) * 1024 + (tid & 3) * 16;

  // read-side 8B-swizzled offset within each 32B half: slot' = l16 ^ ((row>>2)&3);
  // frag row bases are multiples of 16 -> (row>>2)&3 = (l15>>2)&3 per lane.
  const int koff = ((l16 ^ ((l15 >> 2) & 3)) << 3);
  const int aBase = (wr * 64 + l15) * 64 + koff;   // + mi*1024, + h*32
  const int bBase = (wc * 64 + l15) * 64 + koff;   // + ni*1024, + h*32 (B region +8192)

  f32x4_t acc[4][4];
  #pragma unroll
  for (int i = 0; i < 4; ++i)
    #pragma unroll
    for (int j = 0; j < 4; ++j)
      acc[i][j] = (f32x4_t){0.f, 0.f, 0.f, 0.f};

  #define STAGE(bufp, k0) do { \
    GLDS(sgA + (k0), (bufp) + tid * 16); \
    GLDS(sgB0 + (k0), (bufp) + 8192 + tid * 16); \
    GLDS(sgB1 + (k0), (bufp) + 8192 + (tid + 512) * 16); \
  } while (0)

  // prologue: tiles 0,1 staged; vmcnt(3) -> tile0's 3 loads retired
  STAGE(lds[0], 0);
  STAGE(lds[1], BK);
  asm volatile("s_waitcnt vmcnt(3)" ::: "memory");
  __builtin_amdgcn_s_barrier();

  int cur = 0;
  for (int t = 0; t < NT; ++t) {
    if (t + 2 < NT) {
      int stg = cur + 2; if (stg >= 3) stg -= 3;
      STAGE(lds[stg], (t + 2) * BK);
    }
    const uchar* Ar = lds[cur];
    const uchar* Br = lds[cur] + 8192;
    #pragma unroll
    for (int h = 0; h < 2; ++h) {
      long a[4], b[4];
      #pragma unroll
      for (int mi = 0; mi < 4; ++mi)
        a[mi] = *reinterpret_cast<const long*>(Ar + aBase + mi * 1024 + h * 32);
      #pragma unroll
      for (int ni = 0; ni < 4; ++ni)
        b[ni] = *reinterpret_cast<const long*>(Br + bBase + ni * 1024 + h * 32);
      __builtin_amdgcn_s_setprio(1);
      #pragma unroll
      for (int mi = 0; mi < 4; ++mi)
        #pragma unroll
        for (int ni = 0; ni < 4; ++ni)
          acc[mi][ni] = MFMA_FP8(a[mi], b[ni], acc[mi][ni]);
      __builtin_amdgcn_s_setprio(0);
    }
    if (t + 1 < NT) {
      if (t + 2 < NT) asm volatile("s_waitcnt vmcnt(3)" ::: "memory");
      else            asm volatile("s_waitcnt vmcnt(0)" ::: "memory");
      __builtin_amdgcn_s_barrier();
    }
    cur = cur + 1; if (cur >= 3) cur = 0;
  }
  #undef STAGE

  // fused partial-LSE epilogue. acc[mi][ni][j]: row = wr*64+mi*16+l16*4+j,
  // col = wc*64+ni*16+l15 (m89 C/D layout; dtype-independent m121-128)
  const int chunk = nb * 4 + wc;
  #pragma unroll
  for (int mi = 0; mi < 4; ++mi) {
    #pragma unroll
    for (int j = 0; j < 4; ++j) {
      float v0 = acc[mi][0][j], v1 = acc[mi][1][j], v2 = acc[mi][2][j], v3 = acc[mi][3][j];
      float mloc = fmaxf(fmaxf(v0, v1), fmaxf(v2, v3));
      #pragma unroll
      for (int d = 1; d < 16; d <<= 1) mloc = fmaxf(mloc, __shfl_xor(mloc, d));
      float sloc = __expf(v0 - mloc) + __expf(v1 - mloc) +
                   __expf(v2 - mloc) + __expf(v3 - mloc);
      #pragma unroll
      for (int d = 1; d < 16; d <<= 1) sloc += __shfl_xor(sloc, d);
      if (l15 == 0) {
        int grow = mb * 128 + wr * 64 + mi * 16 + l16 * 4 + j;
        part[(size_t)grow * NCHUNK + chunk] = make_float2(mloc, sloc);
      }
    }
  }
}

// ---------------- per-row merge of partials -> nll[row] ----------------
__device__ __forceinline__ void merge_ms(float& m, float& s, float m2, float s2) {
  if (m2 > m) { s = s * __expf(m - m2) + s2; m = m2; }
  else        { s += s2 * __expf(m2 - m); }
}

__global__ void lse_reduce(const float2* __restrict__ part, const float* __restrict__ tgt,
                           const int* __restrict__ targets, float* __restrict__ nll) {
  int row = blockIdx.x;
  const float2* p = part + (size_t)row * NCHUNK;
  float m = -INFINITY, s = 0.f;
  for (int c = threadIdx.x; c < NCHUNK; c += blockDim.x) {
    float2 v = p[c];
    merge_ms(m, s, v.x, v.y);
  }
  #pragma unroll
  for (int d = 1; d < 64; d <<= 1) {
    float m2 = __shfl_xor(m, d), s2 = __shfl_xor(s, d);
    merge_ms(m, s, m2, s2);
  }
  __shared__ float sm[4], ss[4];
  int wid = threadIdx.x >> 6, lane = threadIdx.x & 63;
  if (lane == 0) { sm[wid] = m; ss[wid] = s; }
  __syncthreads();
  if (threadIdx.x == 0) {
    #pragma unroll
    for (int w2 = 1; w2 < 4; ++w2) merge_ms(m, s, sm[w2], ss[w2]);
    int t = targets[row];
    float out = 0.f;
    if (t != IGNORE_INDEX) out = m + logf(s) - tgt[row];
    nll[row] = out;
  }
}

// ---------------- final scalar: sum(nll)/count ----------------
__global__ void final_kernel(const float* __restrict__ nll, const int* __restrict__ targets,
                             float* __restrict__ out) {
  float sum = 0.f, cnt = 0.f;
  for (int i = threadIdx.x; i < Mrows; i += 64) {
    sum += nll[i];
    cnt += (targets[i] != IGNORE_INDEX) ? 1.f : 0.f;
  }
  #pragma unroll
  for (int d = 1; d < 64; d <<= 1) {
    sum += __shfl_xor(sum, d);
    cnt += __shfl_xor(cnt, d);
  }
  if (threadIdx.x == 0)
    out[0] = (cnt == 0.f) ? sum : sum / fmaxf(cnt, 1.f);
}

extern "C" void kernel_launch(void* const* d_in, const int* in_sizes, int n_in,
                              void* d_out, int out_size, void* d_ws, size_t ws_size,
                              hipStream_t stream) {
  const float* hidden = (const float*)d_in[0];   // [2,1024,1024] f32
  const float* weight = (const float*)d_in[1];   // [128000,1024] f32
  const int* targets  = (const int*)d_in[2];     // [2,1024] i32
  float* out = (float*)d_out;

  char* ws = (char*)d_ws;
  size_t off = 0;
  uchar* w8 = (uchar*)(ws + off); off += (size_t)Vc * Dc;                  // 128 MB
  uchar* h8 = (uchar*)(ws + off); off += (size_t)Mrows * Dc;               // 2 MB
  float2* part = (float2*)(ws + off); off += (size_t)Mrows * NCHUNK * sizeof(float2); // 32 MB
  float* tgt = (float*)(ws + off); off += Mrows * sizeof(float);
  float* nll = (float*)(ws + off); off += Mrows * sizeof(float);
  (void)ws_size; (void)in_sizes; (void)n_in; (void)out_size;

  cast_f32_fp8_swz<<<2048, 256, 0, stream>>>(weight, w8, (size_t)Vc * Dc / 8);
  cast_f32_fp8_swz<<<256, 256, 0, stream>>>(hidden, h8, (size_t)Mrows * Dc / 8);
  tgt_kernel<<<Mrows / 4, 256, 0, stream>>>(hidden, weight, targets, tgt);

  gemm_lse_fp8<<<8000, 512, 0, stream>>>(h8, w8, part);  // mb=bid&15, nb=bid>>4

  lse_reduce<<<Mrows, 256, 0, stream>>>(part, tgt, targets, nll);
  final_kernel<<<1, 64, 0, stream>>>(nll, targets, out);
}

// Round 25
// 518.792 us; speedup vs baseline: 3.7749x; 1.0868x over previous
//
#include <hip/hip_runtime.h>
#include <hip/hip_bf16.h>
#include <hip/hip_fp8.h>
#include <math.h>

#define IGNORE_INDEX (-100)

static constexpr int Dc = 1024, Vc = 128000;
static constexpr int Mrows = 2048;        // B*S
static constexpr int Kdim = 1024;
static constexpr int BK = 64;             // fp8: 64 elems = 64 B LDS rows
static constexpr int NT = Kdim / BK;      // 16 K-tiles
static constexpr int NCHUNK = Vc / 64;    // 2000 partial chunks per row

typedef float f32x4_t __attribute__((ext_vector_type(4)));

// ------- cast fp32 -> fp8 e4m3, PRE-SWIZZLED for 64B LDS rows ---------------
// R24 lesson: the 32B-group swizzle is wrong for BK=64 rows (addr/8 mod 16 =
// 8*(l15&1) + slot' -> row term contributes only 1 bit, so slot' must inject
// 3 bits). Within every 64B k-group of a row, 8B slot s is stored at
// s ^ ((row>>1)&7). Bank check (ds_read_b64, 16-lane HW group, l15=2q+r):
// addr/8 mod 16 = 8r + ((4h+l16)^q) -> bijective -> all 32 banks, conflict-free.
__global__ void cast_f32_fp8_swz(const float* __restrict__ in, uchar* __restrict__ out,
                                 size_t n8) {
  size_t i = (size_t)blockIdx.x * blockDim.x + threadIdx.x;
  size_t stride = (size_t)gridDim.x * blockDim.x;
  for (; i < n8; i += stride) {
    size_t byte0 = i * 8;                 // logical fp8 byte index (slot-aligned)
    size_t row = byte0 >> 10;             // 1024 B per K-row
    int s = (int)(byte0 >> 3) & 7;        // 8B slot within 64B group
    int sw = s ^ ((int)(row >> 1) & 7);
    size_t obyte = (byte0 & ~(size_t)63) | ((size_t)sw << 3);
    float4 v0 = *reinterpret_cast<const float4*>(in + byte0);
    float4 v1 = *reinterpret_cast<const float4*>(in + byte0 + 4);
    union { uchar b[8]; unsigned long long u; } p;
    p.b[0] = __hip_fp8_e4m3(v0.x).__x; p.b[1] = __hip_fp8_e4m3(v0.y).__x;
    p.b[2] = __hip_fp8_e4m3(v0.z).__x; p.b[3] = __hip_fp8_e4m3(v0.w).__x;
    p.b[4] = __hip_fp8_e4m3(v1.x).__x; p.b[5] = __hip_fp8_e4m3(v1.y).__x;
    p.b[6] = __hip_fp8_e4m3(v1.z).__x; p.b[7] = __hip_fp8_e4m3(v1.w).__x;
    *reinterpret_cast<unsigned long long*>(out + obyte) = p.u;
  }
}

// ---------------- target logits: fp32 dot(hidden[r], weight[t[r]]) — exact ----
__global__ void tgt_kernel(const float* __restrict__ hidden, const float* __restrict__ weight,
                           const int* __restrict__ targets, float* __restrict__ tgt) {
  int row = blockIdx.x * 4 + (threadIdx.x >> 6);
  int lane = threadIdx.x & 63;
  if (row >= Mrows) return;
  int t = targets[row];
  float sum = 0.f;
  if (t != IGNORE_INDEX) {
    const float* h = hidden + (size_t)row * Kdim;
    const float* wv = weight + (size_t)t * Kdim;
    for (int k = lane * 4; k < Kdim; k += 64 * 4) {
      float4 a = *reinterpret_cast<const float4*>(h + k);
      float4 b = *reinterpret_cast<const float4*>(wv + k);
      sum += a.x * b.x + a.y * b.y + a.z * b.z + a.w * b.w;
    }
  }
  #pragma unroll
  for (int d = 1; d < 64; d <<= 1) sum += __shfl_xor(sum, d);
  if (lane == 0) tgt[row] = sum;
}

// -- 128x256 8-wave 2-BLOCK/CU ring-3 FP8 GEMM (BK=64) + fused partial LSE ---
// R24 verified: BK=64 ring-3 + vmcnt(3) = 463us steady / MfmaUtil 51% but
// with the stale 32B-group swizzle -> 2-way conflicts (6.55e7). This round:
// 64B-group swizzle (cast above); reads use per-half XOR offsets
// koff_h = ((4h + l16) ^ ((l15>>1)&7)) << 3 (frag-row bases are multiples of
// 16 so the row term is per-lane constant). Everything else identical.
#define MFMA_FP8(A, B, C) __builtin_amdgcn_mfma_f32_16x16x32_fp8_fp8((A), (B), (C), 0, 0, 0)
#define GLDS(g, l) __builtin_amdgcn_global_load_lds( \
    (const __attribute__((address_space(1))) void*)(g), \
    (__attribute__((address_space(3))) void*)(l), 16, 0, 0)

__global__ __launch_bounds__(512, 4) void gemm_lse_fp8(const uchar* __restrict__ A8,
                                                       const uchar* __restrict__ B8,
                                                       float2* __restrict__ part) {
  __shared__ uchar lds[3][24576];      // [ring][A(128x64B)=8KB | B(256x64B)=16KB]
  const int tid = threadIdx.x;
  const int wid = tid >> 6, lane = tid & 63;
  const int wr = wid >> 2, wc = wid & 3;        // 2M x 4N wave grid, wave = 64x64 out
  const int l15 = lane & 15, l16 = lane >> 4;
  const int bid = blockIdx.x;
  const int mb = bid & 15;             // 16 M-blocks share one B panel
  const int nb = bid >> 4;             // 0..499

  // staging sources (16B-linear; data pre-swizzled by cast kernel).
  const uchar* gA = A8 + (size_t)(mb * 128) * 1024;
  const uchar* gB = B8 + (size_t)(nb * 256) * 1024;
  const uchar* sgA  = gA + (size_t)(tid >> 2) * 1024 + (tid & 3) * 16;
  const uchar* sgB0 = gB + (size_t)(tid >> 2) * 1024 + (tid & 3) * 16;
  const uchar* sgB1 = gB + (size_t)((tid + 512) >> 2) * 1024 + (tid & 3) * 16;

  // read-side swizzled offsets (per k-half h): slot = 4h + l16 ->
  // phys = slot ^ ((l15>>1)&7), byte off = phys*8.
  const int fsw = (l15 >> 1) & 7;
  const int koff0 = ((l16 ^ fsw) << 3);
  const int koff1 = (((4 | l16) ^ fsw) << 3);
  const int aBase = (wr * 64 + l15) * 64;   // + mi*1024 + koff_h
  const int bBase = (wc * 64 + l15) * 64;   // + ni*1024 + koff_h (B region +8192)

  f32x4_t acc[4][4];
  #pragma unroll
  for (int i = 0; i < 4; ++i)
    #pragma unroll
    for (int j = 0; j < 4; ++j)
      acc[i][j] = (f32x4_t){0.f, 0.f, 0.f, 0.f};

  #define STAGE(bufp, k0) do { \
    GLDS(sgA + (k0), (bufp) + tid * 16); \
    GLDS(sgB0 + (k0), (bufp) + 8192 + tid * 16); \
    GLDS(sgB1 + (k0), (bufp) + 8192 + (tid + 512) * 16); \
  } while (0)

  // prologue: tiles 0,1 staged; vmcnt(3) -> tile0's 3 loads retired
  STAGE(lds[0], 0);
  STAGE(lds[1], BK);
  asm volatile("s_waitcnt vmcnt(3)" ::: "memory");
  __builtin_amdgcn_s_barrier();

  int cur = 0;
  for (int t = 0; t < NT; ++t) {
    if (t + 2 < NT) {
      int stg = cur + 2; if (stg >= 3) stg -= 3;
      STAGE(lds[stg], (t + 2) * BK);
    }
    const uchar* Ar = lds[cur];
    const uchar* Br = lds[cur] + 8192;
    #pragma unroll
    for (int h = 0; h < 2; ++h) {
      const int koff = h ? koff1 : koff0;
      long a[4], b[4];
      #pragma unroll
      for (int mi = 0; mi < 4; ++mi)
        a[mi] = *reinterpret_cast<const long*>(Ar + aBase + mi * 1024 + koff);
      #pragma unroll
      for (int ni = 0; ni < 4; ++ni)
        b[ni] = *reinterpret_cast<const long*>(Br + bBase + ni * 1024 + koff);
      __builtin_amdgcn_s_setprio(1);
      #pragma unroll
      for (int mi = 0; mi < 4; ++mi)
        #pragma unroll
        for (int ni = 0; ni < 4; ++ni)
          acc[mi][ni] = MFMA_FP8(a[mi], b[ni], acc[mi][ni]);
      __builtin_amdgcn_s_setprio(0);
    }
    if (t + 1 < NT) {
      if (t + 2 < NT) asm volatile("s_waitcnt vmcnt(3)" ::: "memory");
      else            asm volatile("s_waitcnt vmcnt(0)" ::: "memory");
      __builtin_amdgcn_s_barrier();
    }
    cur = cur + 1; if (cur >= 3) cur = 0;
  }
  #undef STAGE

  // fused partial-LSE epilogue. acc[mi][ni][j]: row = wr*64+mi*16+l16*4+j,
  // col = wc*64+ni*16+l15 (m89 C/D layout; dtype-independent m121-128)
  const int chunk = nb * 4 + wc;
  #pragma unroll
  for (int mi = 0; mi < 4; ++mi) {
    #pragma unroll
    for (int j = 0; j < 4; ++j) {
      float v0 = acc[mi][0][j], v1 = acc[mi][1][j], v2 = acc[mi][2][j], v3 = acc[mi][3][j];
      float mloc = fmaxf(fmaxf(v0, v1), fmaxf(v2, v3));
      #pragma unroll
      for (int d = 1; d < 16; d <<= 1) mloc = fmaxf(mloc, __shfl_xor(mloc, d));
      float sloc = __expf(v0 - mloc) + __expf(v1 - mloc) +
                   __expf(v2 - mloc) + __expf(v3 - mloc);
      #pragma unroll
      for (int d = 1; d < 16; d <<= 1) sloc += __shfl_xor(sloc, d);
      if (l15 == 0) {
        int grow = mb * 128 + wr * 64 + mi * 16 + l16 * 4 + j;
        part[(size_t)grow * NCHUNK + chunk] = make_float2(mloc, sloc);
      }
    }
  }
}

// ---------------- per-row merge of partials -> nll[row] ----------------
__device__ __forceinline__ void merge_ms(float& m, float& s, float m2, float s2) {
  if (m2 > m) { s = s * __expf(m - m2) + s2; m = m2; }
  else        { s += s2 * __expf(m2 - m); }
}

__global__ void lse_reduce(const float2* __restrict__ part, const float* __restrict__ tgt,
                           const int* __restrict__ targets, float* __restrict__ nll) {
  int row = blockIdx.x;
  const float2* p = part + (size_t)row * NCHUNK;
  float m = -INFINITY, s = 0.f;
  for (int c = threadIdx.x; c < NCHUNK; c += blockDim.x) {
    float2 v = p[c];
    merge_ms(m, s, v.x, v.y);
  }
  #pragma unroll
  for (int d = 1; d < 64; d <<= 1) {
    float m2 = __shfl_xor(m, d), s2 = __shfl_xor(s, d);
    merge_ms(m, s, m2, s2);
  }
  __shared__ float sm[4], ss[4];
  int wid = threadIdx.x >> 6, lane = threadIdx.x & 63;
  if (lane == 0) { sm[wid] = m; ss[wid] = s; }
  __syncthreads();
  if (threadIdx.x == 0) {
    #pragma unroll
    for (int w2 = 1; w2 < 4; ++w2) merge_ms(m, s, sm[w2], ss[w2]);
    int t = targets[row];
    float out = 0.f;
    if (t != IGNORE_INDEX) out = m + logf(s) - tgt[row];
    nll[row] = out;
  }
}

// ---------------- final scalar: sum(nll)/count ----------------
__global__ void final_kernel(const float* __restrict__ nll, const int* __restrict__ targets,
                             float* __restrict__ out) {
  float sum = 0.f, cnt = 0.f;
  for (int i = threadIdx.x; i < Mrows; i += 64) {
    sum += nll[i];
    cnt += (targets[i] != IGNORE_INDEX) ? 1.f : 0.f;
  }
  #pragma unroll
  for (int d = 1; d < 64; d <<= 1) {
    sum += __shfl_xor(sum, d);
    cnt += __shfl_xor(cnt, d);
  }
  if (threadIdx.x == 0)
    out[0] = (cnt == 0.f) ? sum : sum / fmaxf(cnt, 1.f);
}

extern "C" void kernel_launch(void* const* d_in, const int* in_sizes, int n_in,
                              void* d_out, int out_size, void* d_ws, size_t ws_size,
                              hipStream_t stream) {
  const float* hidden = (const float*)d_in[0];   // [2,1024,1024] f32
  const float* weight = (const float*)d_in[1];   // [128000,1024] f32
  const int* targets  = (const int*)d_in[2];     // [2,1024] i32
  float* out = (float*)d_out;

  char* ws = (char*)d_ws;
  size_t off = 0;
  uchar* w8 = (uchar*)(ws + off); off += (size_t)Vc * Dc;                  // 128 MB
  uchar* h8 = (uchar*)(ws + off); off += (size_t)Mrows * Dc;               // 2 MB
  float2* part = (float2*)(ws + off); off += (size_t)Mrows * NCHUNK * sizeof(float2); // 32 MB
  float* tgt = (float*)(ws + off); off += Mrows * sizeof(float);
  float* nll = (float*)(ws + off); off += Mrows * sizeof(float);
  (void)ws_size; (void)in_sizes; (void)n_in; (void)out_size;

  cast_f32_fp8_swz<<<2048, 256, 0, stream>>>(weight, w8, (size_t)Vc * Dc / 8);
  cast_f32_fp8_swz<<<256, 256, 0, stream>>>(hidden, h8, (size_t)Mrows * Dc / 8);
  tgt_kernel<<<Mrows / 4, 256, 0, stream>>>(hidden, weight, targets, tgt);

  gemm_lse_fp8<<<8000, 512, 0, stream>>>(h8, w8, part);  // mb=bid&15, nb=bid>>4

  lse_reduce<<<Mrows, 256, 0, stream>>>(part, tgt, targets, nll);
  final_kernel<<<1, 64, 0, stream>>>(nll, targets, out);
}